// Round 8
// baseline (940.043 us; speedup 1.0000x reference)
//
#include <hip/hip_runtime.h>

typedef _Float16 f16;
typedef f16 f16x2 __attribute__((ext_vector_type(2)));
typedef f16 f16x8 __attribute__((ext_vector_type(8)));
typedef float f32x4 __attribute__((ext_vector_type(4)));
typedef float f32x2 __attribute__((ext_vector_type(2)));

#define MFMA16(a, b, c) __builtin_amdgcn_mfma_f32_16x16x32_f16((a), (b), (c), 0, 0, 0)

static __device__ __forceinline__ f16x8 cvt8(const float* __restrict__ p) {
    f32x4 p0 = *(const f32x4*)p;
    f32x4 p1 = *(const f32x4*)(p + 4);
    f16x8 a;
    a[0] = (f16)p0[0]; a[1] = (f16)p0[1]; a[2] = (f16)p0[2]; a[3] = (f16)p0[3];
    a[4] = (f16)p1[0]; a[5] = (f16)p1[1]; a[6] = (f16)p1[2]; a[7] = (f16)p1[3];
    return a;
}

// Fused prep: blocks [0,48) repack weights to B-fragment order; [48,48+CB)
// count in-degrees; rest classify nodes by depth into recs[].x.
__global__ __launch_bounds__(256) void k_prep(
        const float* __restrict__ pw, const float* __restrict__ mw1,
        const float* __restrict__ mw2, const float* __restrict__ uw1,
        const float* __restrict__ uw2,
        f16* __restrict__ pwp, f16* __restrict__ mw1p, f16* __restrict__ mw2p,
        f16* __restrict__ uw1p, f16* __restrict__ uw2p,
        const int* __restrict__ ei, int* __restrict__ degv,
        const int* __restrict__ dep, int* __restrict__ dcnt,
        int4* __restrict__ recs, int CB, int E, int N) {
    __shared__ int lcnt[4];
    __shared__ int lbase[4];
    int b = blockIdx.x;
    int t = threadIdx.x;
    if (b < 48) {
        const float* W; f16* out; int fb;
        if (b < 8)       { W = pw;  out = pwp;  fb = b; }
        else if (b < 16) { W = mw1; out = mw1p; fb = b - 8; }
        else if (b < 24) { W = mw2; out = mw2p; fb = b - 16; }
        else if (b < 40) { W = uw1; out = uw1p; fb = b - 24; }
        else             { W = uw2; out = uw2p; fb = b - 40; }
        int idx = fb * 256 + t;
        int lane = idx & 63;
        int nt = (idx >> 6) & 7;
        int kt = idx >> 9;
        int colx = lane & 15, quad = lane >> 4;
        f16* o = out + (size_t)idx * 8;
        const float* wb = W + (size_t)(kt * 32 + quad * 8) * 128 + nt * 16 + colx;
#pragma unroll
        for (int j = 0; j < 8; j++) o[j] = (f16)wb[(size_t)j * 128];
    } else if (b < 48 + CB) {
        int e = (b - 48) * 256 + t;
        if (e < E) atomicAdd(&degv[ei[E + e]], 1);
    } else {
        if (t < 4) lcnt[t] = 0;
        __syncthreads();
        int v = (b - 48 - CB) * 256 + t;
        int d = (v < N) ? dep[v] : 0;
        int p = -1;
        if (d >= 1 && d <= 4) p = atomicAdd(&lcnt[d - 1], 1);
        __syncthreads();
        if (t < 4) lbase[t] = (lcnt[t] > 0) ? atomicAdd(&dcnt[t], lcnt[t]) : 0;
        __syncthreads();
        if (d >= 1 && d <= 4) recs[(size_t)(d - 1) * N + lbase[d - 1] + p].x = v;
    }
}

// Blocks [0,SB): scan stage A. Rest: proj — h = x@pw+pb; t = h@mw1[0:128]+mb1.
__global__ __launch_bounds__(256) void k_mid(
        const int* __restrict__ degv, int* __restrict__ bsum, int SB,
        const float* __restrict__ x, const f16* __restrict__ pwp,
        const f16* __restrict__ mw1p, const float* __restrict__ pb,
        const float* __restrict__ mb1, float* __restrict__ h,
        f16* __restrict__ t, int N) {
    __shared__ __align__(16) f16 lds[4][16 * 136];
    __shared__ int wsum[4];
    int tid = threadIdx.x;
    if ((int)blockIdx.x < SB) {
        int idx = blockIdx.x * 256 + tid;
        int v = (idx < N) ? degv[idx] : 0;
#pragma unroll
        for (int off = 32; off; off >>= 1) v += __shfl_down(v, off, 64);
        if ((tid & 63) == 0) wsum[tid >> 6] = v;
        __syncthreads();
        if (tid == 0) bsum[blockIdx.x] = wsum[0] + wsum[1] + wsum[2] + wsum[3];
        return;
    }
    int lane = tid & 63, w = tid >> 6;
    int colx = lane & 15, quad = lane >> 4;
    int base = ((blockIdx.x - SB) * 4 + w) * 16;
    int arow = base + colx;
    int u = arow < N ? arow : N - 1;

    f32x4 c1[8];
#pragma unroll
    for (int nt = 0; nt < 8; nt++) c1[nt] = (f32x4){0.f, 0.f, 0.f, 0.f};
#pragma unroll
    for (int kt = 0; kt < 4; kt++) {
        f16x8 a = cvt8(x + (size_t)u * 128 + kt * 32 + quad * 8);
#pragma unroll
        for (int nt = 0; nt < 8; nt++) {
            f16x8 b = *(const f16x8*)(pwp + ((size_t)(kt * 8 + nt) * 64 + lane) * 8);
            c1[nt] = MFMA16(a, b, c1[nt]);
        }
    }
#pragma unroll
    for (int nt = 0; nt < 8; nt++) {
        float bias = pb[nt * 16 + colx];
#pragma unroll
        for (int reg = 0; reg < 4; reg++) {
            int row = quad * 4 + reg;
            int node = base + row;
            float v = c1[nt][reg] + bias;
            lds[w][row * 136 + nt * 16 + colx] = (f16)v;
            if (node < N) h[(size_t)node * 128 + nt * 16 + colx] = v;
        }
    }
    f32x4 c2[8];
#pragma unroll
    for (int nt = 0; nt < 8; nt++) c2[nt] = (f32x4){0.f, 0.f, 0.f, 0.f};
#pragma unroll
    for (int kt = 0; kt < 4; kt++) {
        f16x8 a = *(const f16x8*)&lds[w][colx * 136 + kt * 32 + quad * 8];
#pragma unroll
        for (int nt = 0; nt < 8; nt++) {
            f16x8 b = *(const f16x8*)(mw1p + ((size_t)(kt * 8 + nt) * 64 + lane) * 8);
            c2[nt] = MFMA16(a, b, c2[nt]);
        }
    }
#pragma unroll
    for (int nt = 0; nt < 8; nt++) {
        float bias = mb1[nt * 16 + colx];
#pragma unroll
        for (int reg = 0; reg < 4; reg++) {
            int node = base + quad * 4 + reg;
            if (node < N) t[(size_t)node * 128 + nt * 16 + colx] = (f16)(c2[nt][reg] + bias);
        }
    }
}

__global__ __launch_bounds__(256) void k_scanC(const int* __restrict__ degv,
                                               const int* __restrict__ bsum,
                                               int* __restrict__ rowp, int N, int E) {
    __shared__ int lds[256];
    __shared__ int wo[4];
    int b = blockIdx.x, t = threadIdx.x;
    int idx = b * 256 + t;
    int v = (idx < N) ? degv[idx] : 0;
    lds[t] = v;
    __syncthreads();
#pragma unroll
    for (int d = 1; d < 256; d <<= 1) {
        int u = (t >= d) ? lds[t - d] : 0;
        __syncthreads();
        lds[t] += u;
        __syncthreads();
    }
    int off = 0;
    for (int j = t; j < b; j += 256) off += bsum[j];
#pragma unroll
    for (int o = 32; o; o >>= 1) off += __shfl_down(off, o, 64);
    if ((t & 63) == 0) wo[t >> 6] = off;
    __syncthreads();
    int boff = wo[0] + wo[1] + wo[2] + wo[3];
    if (idx < N) rowp[idx] = boff + lds[t] - v;
    if (b == 0 && t == 0) rowp[N] = E;
}

// Scatter edges into CSR (fused {src, edge_attr} int2 records) + fill recs e0/e1.
__global__ __launch_bounds__(256) void k_scat(const int* __restrict__ ei,
                                              const float* __restrict__ eattr,
                                              const int* __restrict__ rowp,
                                              int* __restrict__ cur,
                                              int2* __restrict__ esea,
                                              int4* __restrict__ recs,
                                              const int* __restrict__ dcnt,
                                              int E, int N) {
    int gtid = blockIdx.x * 256 + threadIdx.x;
    int gsz = gridDim.x * 256;
    for (int e = gtid; e < E; e += gsz) {
        int s = ei[e], d = ei[E + e];
        int p = rowp[d] + atomicAdd(&cur[d], 1);
        esea[p] = (int2){s, __float_as_int(eattr[e])};
    }
    for (int d4 = 0; d4 < 4; d4++) {
        int cnt = dcnt[d4];
        for (int i = gtid; i < cnt; i += gsz) {
            int4* r = &recs[(size_t)d4 * N + i];
            int u = r->x;
            r->y = rowp[u];
            r->z = rowp[u + 1];
        }
    }
}

// Per-depth msg: one wave per dst node (2-node paired prefetch).
// agg[u] = mean(relu(relu(t[src]+ea*w1row) @ mw2 + mb2)) over u's edges.
// __launch_bounds__(256,4): force VGPR<=128 -> 16 waves/CU (was 144 VGPR ->
// 12/CU cap, ~2.6 measured). Latency-bound: more residency = more overlap.
__global__ __launch_bounds__(256, 4) void k_m(
        const f16* __restrict__ t, const float* __restrict__ mw1,
        const float* __restrict__ mb2, const f16* __restrict__ mw2p,
        const int2* __restrict__ esea,
        const int4* __restrict__ recs, const int* __restrict__ dcnt,
        int dIdx, f16* __restrict__ agg, int N) {
    const int tid = threadIdx.x;
    const int lane = tid & 63;
    const int colx = lane & 15, quad = lane >> 4;
    const int gwv = blockIdx.x * 4 + (tid >> 6), nwv = gridDim.x * 4;
    const int cnt = dcnt[dIdx];

    const float* w1r = mw1 + 128 * 128;
    f16x8 w1h[4];
#pragma unroll
    for (int kt = 0; kt < 4; kt++) {
        f32x4 q0 = *(const f32x4*)(w1r + kt * 32 + quad * 8);
        f32x4 q1 = *(const f32x4*)(w1r + kt * 32 + quad * 8 + 4);
        w1h[kt][0] = (f16)q0[0]; w1h[kt][1] = (f16)q0[1];
        w1h[kt][2] = (f16)q0[2]; w1h[kt][3] = (f16)q0[3];
        w1h[kt][4] = (f16)q1[0]; w1h[kt][5] = (f16)q1[1];
        w1h[kt][6] = (f16)q1[2]; w1h[kt][7] = (f16)q1[3];
    }
    float mb2v[8];
#pragma unroll
    for (int nt = 0; nt < 8; nt++) mb2v[nt] = mb2[nt * 16 + colx];

    struct Pre { int u, e0, e1; f16 eah; f16x8 tv[4]; };
    auto load_pre = [&](int n) {
        Pre p;
        int4 r = recs[(size_t)dIdx * N + n];
        p.u = r.x; p.e0 = r.y; p.e1 = r.z;
        int lim = p.e1 - 1; if (lim < 0) lim = 0;
        int es = p.e0 + colx; if (es > lim) es = lim;
        int2 er = esea[es];
        p.eah = (f16)__int_as_float(er.y);
        const f16* trow = t + (size_t)er.x * 128;
#pragma unroll
        for (int kt = 0; kt < 4; kt++)
            p.tv[kt] = *(const f16x8*)(trow + kt * 32 + quad * 8);
        return p;
    };
    auto build_afr = [&](const f16x8* tv, f16 eah, f16x8* afr) {
#pragma unroll
        for (int kt = 0; kt < 4; kt++) {
            f16x8 v = tv[kt];
            f16x8 o;
#pragma unroll
            for (int j = 0; j < 8; j++) {
                f16 q = v[j] + eah * w1h[kt][j];
                o[j] = q > (f16)0 ? q : (f16)0;
            }
            afr[kt] = o;
        }
    };
    auto tile_acc = [&](f16x8* afr, int bs, int e1, float* aggv) {
#pragma unroll
        for (int nt = 0; nt < 8; nt++) {
            f32x4 c = (f32x4){0.f, 0.f, 0.f, 0.f};
#pragma unroll
            for (int kt = 0; kt < 4; kt++) {
                f16x8 b = *(const f16x8*)(mw2p + ((size_t)(kt * 8 + nt) * 64 + lane) * 8);
                c = MFMA16(afr[kt], b, c);
            }
#pragma unroll
            for (int reg = 0; reg < 4; reg++)
                if (bs + quad * 4 + reg < e1) aggv[nt] += fmaxf(c[reg] + mb2v[nt], 0.f);
        }
    };
    auto process = [&](const Pre& p) {
        float aggv[8] = {0.f, 0.f, 0.f, 0.f, 0.f, 0.f, 0.f, 0.f};
        f16x8 afr[4];
        build_afr(p.tv, p.eah, afr);
        tile_acc(afr, p.e0, p.e1, aggv);
        for (int bs = p.e0 + 16; bs < p.e1; bs += 16) {
            int lim = p.e1 - 1;
            int es = bs + colx; if (es > lim) es = lim;
            int2 er = esea[es];
            f16 eah = (f16)__int_as_float(er.y);
            const f16* trow = t + (size_t)er.x * 128;
            f16x8 tv[4];
#pragma unroll
            for (int kt = 0; kt < 4; kt++)
                tv[kt] = *(const f16x8*)(trow + kt * 32 + quad * 8);
            build_afr(tv, eah, afr);
            tile_acc(afr, bs, p.e1, aggv);
        }
        int deg = p.e1 - p.e0;
        float inv = 1.f / (float)(deg > 1 ? deg : 1);
#pragma unroll
        for (int nt = 0; nt < 8; nt++) {
            float s = aggv[nt];
            s += __shfl_xor(s, 16, 64);
            s += __shfl_xor(s, 32, 64);
            if (quad == 0) agg[(size_t)p.u * 128 + nt * 16 + colx] = (f16)(s * inv);
        }
    };
    int stride2 = nwv * 2;
    for (int base = gwv * 2; base < cnt; base += stride2) {
        Pre p0 = load_pre(base);
        bool has1 = (base + 1) < cnt;
        if (has1) {
            Pre p1 = load_pre(base + 1);
            process(p0);
            process(p1);
        } else {
            process(p0);
        }
    }
}

// Per-depth update, TILED: one wave = 16 nodes of this depth.
// __launch_bounds__(256,3): cap VGPR ~170 (was 256 -> 8 waves/CU; now 12).
__global__ __launch_bounds__(256, 3) void k_u(
        float* h, f16* t, const f16* __restrict__ agg,
        const f16* __restrict__ uw1p, const f16* __restrict__ uw2p,
        const f16* __restrict__ mw1p,
        const float* __restrict__ ub1, const float* __restrict__ ub2,
        const float* __restrict__ mb1,
        const int4* __restrict__ recs, const int* __restrict__ dcnt,
        int dIdx, int N) {
    __shared__ __align__(16) f16 shb[4][2][16 * 136];
    const int tid = threadIdx.x;
    const int lane = tid & 63, w = tid >> 6;
    const int colx = lane & 15, quad = lane >> 4;
    const int gwv = blockIdx.x * 4 + w, nwv = gridDim.x * 4;
    const int cnt = dcnt[dIdx];
    const int ntiles = (cnt + 15) >> 4;

    for (int tb = gwv; tb < ntiles; tb += nwv) {
        int base = tb * 16;
        int aidx = base + colx;
        int ua = (aidx < cnt) ? recs[(size_t)dIdx * N + aidx].x : 0;
        int un[4];
        bool uvalid[4];
#pragma unroll
        for (int reg = 0; reg < 4; reg++) {
            int node = base + quad * 4 + reg;
            uvalid[reg] = node < cnt;
            un[reg] = uvalid[reg] ? recs[(size_t)dIdx * N + node].x : 0;
        }

        f32x4 c1[8];
#pragma unroll
        for (int nt = 0; nt < 8; nt++) c1[nt] = (f32x4){0.f, 0.f, 0.f, 0.f};
#pragma unroll
        for (int kt = 0; kt < 8; kt++) {
            f16x8 a;
            if (kt < 4)
                a = cvt8(h + (size_t)ua * 128 + kt * 32 + quad * 8);
            else
                a = *(const f16x8*)(agg + (size_t)ua * 128 + (kt - 4) * 32 + quad * 8);
#pragma unroll
            for (int nt = 0; nt < 8; nt++) {
                f16x8 b = *(const f16x8*)(uw1p + ((size_t)(kt * 8 + nt) * 64 + lane) * 8);
                c1[nt] = MFMA16(a, b, c1[nt]);
            }
        }
#pragma unroll
        for (int nt = 0; nt < 8; nt++) {
            float bias = ub1[nt * 16 + colx];
#pragma unroll
            for (int reg = 0; reg < 4; reg++) {
                int row = quad * 4 + reg;
                shb[w][0][row * 136 + nt * 16 + colx] = (f16)fmaxf(c1[nt][reg] + bias, 0.f);
            }
        }
        f32x4 c2[8];
#pragma unroll
        for (int nt = 0; nt < 8; nt++) c2[nt] = (f32x4){0.f, 0.f, 0.f, 0.f};
#pragma unroll
        for (int kt = 0; kt < 4; kt++) {
            f16x8 a = *(const f16x8*)&shb[w][0][colx * 136 + kt * 32 + quad * 8];
#pragma unroll
            for (int nt = 0; nt < 8; nt++) {
                f16x8 b = *(const f16x8*)(uw2p + ((size_t)(kt * 8 + nt) * 64 + lane) * 8);
                c2[nt] = MFMA16(a, b, c2[nt]);
            }
        }
#pragma unroll
        for (int nt = 0; nt < 8; nt++) {
            float bias = ub2[nt * 16 + colx];
#pragma unroll
            for (int reg = 0; reg < 4; reg++) {
                int row = quad * 4 + reg;
                float v = fmaxf(c2[nt][reg] + bias, 0.f);
                shb[w][1][row * 136 + nt * 16 + colx] = (f16)v;
                if (uvalid[reg]) h[(size_t)un[reg] * 128 + nt * 16 + colx] = v;
            }
        }
        f32x4 c3[8];
#pragma unroll
        for (int nt = 0; nt < 8; nt++) c3[nt] = (f32x4){0.f, 0.f, 0.f, 0.f};
#pragma unroll
        for (int kt = 0; kt < 4; kt++) {
            f16x8 a = *(const f16x8*)&shb[w][1][colx * 136 + kt * 32 + quad * 8];
#pragma unroll
            for (int nt = 0; nt < 8; nt++) {
                f16x8 b = *(const f16x8*)(mw1p + ((size_t)(kt * 8 + nt) * 64 + lane) * 8);
                c3[nt] = MFMA16(a, b, c3[nt]);
            }
        }
#pragma unroll
        for (int nt = 0; nt < 8; nt++) {
            float bias = mb1[nt * 16 + colx];
#pragma unroll
            for (int reg = 0; reg < 4; reg++) {
                if (uvalid[reg])
                    t[(size_t)un[reg] * 128 + nt * 16 + colx] = (f16)(c3[nt][reg] + bias);
            }
        }
    }
}

extern "C" void kernel_launch(void* const* d_in, const int* in_sizes, int n_in,
                              void* d_out, int out_size, void* d_ws, size_t ws_size,
                              hipStream_t stream) {
    const float* x    = (const float*)d_in[0];
    const int*   ei   = (const int*)d_in[1];
    const float* eatt = (const float*)d_in[2];
    const int*   dep  = (const int*)d_in[3];
    const float* pw   = (const float*)d_in[4];
    const float* pb   = (const float*)d_in[5];
    const float* mw1  = (const float*)d_in[6];
    const float* mb1  = (const float*)d_in[7];
    const float* mw2  = (const float*)d_in[8];
    const float* mb2  = (const float*)d_in[9];
    const float* uw1  = (const float*)d_in[10];
    const float* ub1  = (const float*)d_in[11];
    const float* uw2  = (const float*)d_in[12];
    const float* ub2  = (const float*)d_in[13];
    float* h = (float*)d_out;

    int N = in_sizes[3];
    int E = in_sizes[1] / 2;
    int NB = (N + 255) / 256;
    int CB = (E + 255) / 256;

    char* ws = (char*)d_ws;
    size_t o = 0;
    auto alloc = [&](size_t bytes) -> char* {
        char* p = ws + o;
        o += (bytes + 255) & ~(size_t)255;
        return p;
    };
    f16*   t    = (f16*)alloc((size_t)N * 128 * 2);
    f16*   agg  = (f16*)alloc((size_t)N * 128 * 2);
    char*  z0   = (char*)alloc(0);
    int*   degv = (int*)alloc((size_t)N * 4);
    int*   cur  = (int*)alloc((size_t)N * 4);
    int*   dcnt = (int*)alloc(64);
    size_t zbytes = (size_t)((char*)alloc(0) - z0);
    int*   rowp = (int*)alloc((size_t)(N + 1) * 4);
    int*   bsum = (int*)alloc((size_t)NB * 4);
    int2*  esea = (int2*)alloc((size_t)E * 8);
    int4*  recs = (int4*)alloc((size_t)4 * N * 16);
    f16*   pwp  = (f16*)alloc(128 * 128 * 2);
    f16*   mw1p = (f16*)alloc(128 * 128 * 2);
    f16*   mw2p = (f16*)alloc(128 * 128 * 2);
    f16*   uw1p = (f16*)alloc(256 * 128 * 2);
    f16*   uw2p = (f16*)alloc(128 * 128 * 2);

    hipMemsetAsync(z0, 0, zbytes, stream);

    k_prep<<<48 + CB + NB, 256, 0, stream>>>(pw, mw1, mw2, uw1, uw2,
                                             pwp, mw1p, mw2p, uw1p, uw2p,
                                             ei, degv, dep, dcnt, recs, CB, E, N);
    int PB = (N + 63) / 64;
    k_mid<<<NB + PB, 256, 0, stream>>>(degv, bsum, NB, x, pwp, mw1p, pb, mb1,
                                       h, t, N);
    k_scanC<<<NB, 256, 0, stream>>>(degv, bsum, rowp, N, E);
    k_scat<<<CB, 256, 0, stream>>>(ei, eatt, rowp, cur, esea, recs, dcnt, E, N);

    for (int d = 0; d < 4; d++) {
        k_m<<<2048, 256, 0, stream>>>(t, mw1, mb2, mw2p, esea, recs, dcnt,
                                      d, agg, N);
        k_u<<<256, 256, 0, stream>>>(h, t, agg, uw1p, uw2p, mw1p, ub1, ub2,
                                     mb1, recs, dcnt, d, N);
    }
}

// Round 9
// 429.301 us; speedup vs baseline: 2.1897x; 2.1897x over previous
//
#include <hip/hip_runtime.h>

typedef _Float16 f16;
typedef f16 f16x2 __attribute__((ext_vector_type(2)));
typedef f16 f16x8 __attribute__((ext_vector_type(8)));
typedef float f32x4 __attribute__((ext_vector_type(4)));
typedef float f32x2 __attribute__((ext_vector_type(2)));

#define MFMA16(a, b, c) __builtin_amdgcn_mfma_f32_16x16x32_f16((a), (b), (c), 0, 0, 0)

static __device__ __forceinline__ f16x8 cvt8(const float* __restrict__ p) {
    f32x4 p0 = *(const f32x4*)p;
    f32x4 p1 = *(const f32x4*)(p + 4);
    f16x8 a;
    a[0] = (f16)p0[0]; a[1] = (f16)p0[1]; a[2] = (f16)p0[2]; a[3] = (f16)p0[3];
    a[4] = (f16)p1[0]; a[5] = (f16)p1[1]; a[6] = (f16)p1[2]; a[7] = (f16)p1[3];
    return a;
}

// Fused prep: blocks [0,48) repack weights to B-fragment order; [48,48+CB)
// count in-degrees; rest classify nodes by depth into recs[].x.
__global__ __launch_bounds__(256) void k_prep(
        const float* __restrict__ pw, const float* __restrict__ mw1,
        const float* __restrict__ mw2, const float* __restrict__ uw1,
        const float* __restrict__ uw2,
        f16* __restrict__ pwp, f16* __restrict__ mw1p, f16* __restrict__ mw2p,
        f16* __restrict__ uw1p, f16* __restrict__ uw2p,
        const int* __restrict__ ei, int* __restrict__ degv,
        const int* __restrict__ dep, int* __restrict__ dcnt,
        int4* __restrict__ recs, int CB, int E, int N) {
    __shared__ int lcnt[4];
    __shared__ int lbase[4];
    int b = blockIdx.x;
    int t = threadIdx.x;
    if (b < 48) {
        const float* W; f16* out; int fb;
        if (b < 8)       { W = pw;  out = pwp;  fb = b; }
        else if (b < 16) { W = mw1; out = mw1p; fb = b - 8; }
        else if (b < 24) { W = mw2; out = mw2p; fb = b - 16; }
        else if (b < 40) { W = uw1; out = uw1p; fb = b - 24; }
        else             { W = uw2; out = uw2p; fb = b - 40; }
        int idx = fb * 256 + t;
        int lane = idx & 63;
        int nt = (idx >> 6) & 7;
        int kt = idx >> 9;
        int colx = lane & 15, quad = lane >> 4;
        f16* o = out + (size_t)idx * 8;
        const float* wb = W + (size_t)(kt * 32 + quad * 8) * 128 + nt * 16 + colx;
#pragma unroll
        for (int j = 0; j < 8; j++) o[j] = (f16)wb[(size_t)j * 128];
    } else if (b < 48 + CB) {
        int e = (b - 48) * 256 + t;
        if (e < E) atomicAdd(&degv[ei[E + e]], 1);
    } else {
        if (t < 4) lcnt[t] = 0;
        __syncthreads();
        int v = (b - 48 - CB) * 256 + t;
        int d = (v < N) ? dep[v] : 0;
        int p = -1;
        if (d >= 1 && d <= 4) p = atomicAdd(&lcnt[d - 1], 1);
        __syncthreads();
        if (t < 4) lbase[t] = (lcnt[t] > 0) ? atomicAdd(&dcnt[t], lcnt[t]) : 0;
        __syncthreads();
        if (d >= 1 && d <= 4) recs[(size_t)(d - 1) * N + lbase[d - 1] + p].x = v;
    }
}

// Blocks [0,SB): scan stage A. Rest: proj — h = x@pw+pb (f32 out + f16 shadow
// hh); t = h@mw1[0:128]+mb1.
__global__ __launch_bounds__(256) void k_mid(
        const int* __restrict__ degv, int* __restrict__ bsum, int SB,
        const float* __restrict__ x, const f16* __restrict__ pwp,
        const f16* __restrict__ mw1p, const float* __restrict__ pb,
        const float* __restrict__ mb1, float* __restrict__ h,
        f16* __restrict__ hh, f16* __restrict__ t, int N) {
    __shared__ __align__(16) f16 lds[4][16 * 136];
    __shared__ int wsum[4];
    int tid = threadIdx.x;
    if ((int)blockIdx.x < SB) {
        int idx = blockIdx.x * 256 + tid;
        int v = (idx < N) ? degv[idx] : 0;
#pragma unroll
        for (int off = 32; off; off >>= 1) v += __shfl_down(v, off, 64);
        if ((tid & 63) == 0) wsum[tid >> 6] = v;
        __syncthreads();
        if (tid == 0) bsum[blockIdx.x] = wsum[0] + wsum[1] + wsum[2] + wsum[3];
        return;
    }
    int lane = tid & 63, w = tid >> 6;
    int colx = lane & 15, quad = lane >> 4;
    int base = ((blockIdx.x - SB) * 4 + w) * 16;
    int arow = base + colx;
    int u = arow < N ? arow : N - 1;

    f32x4 c1[8];
#pragma unroll
    for (int nt = 0; nt < 8; nt++) c1[nt] = (f32x4){0.f, 0.f, 0.f, 0.f};
#pragma unroll
    for (int kt = 0; kt < 4; kt++) {
        f16x8 a = cvt8(x + (size_t)u * 128 + kt * 32 + quad * 8);
#pragma unroll
        for (int nt = 0; nt < 8; nt++) {
            f16x8 b = *(const f16x8*)(pwp + ((size_t)(kt * 8 + nt) * 64 + lane) * 8);
            c1[nt] = MFMA16(a, b, c1[nt]);
        }
    }
#pragma unroll
    for (int nt = 0; nt < 8; nt++) {
        float bias = pb[nt * 16 + colx];
#pragma unroll
        for (int reg = 0; reg < 4; reg++) {
            int row = quad * 4 + reg;
            int node = base + row;
            float v = c1[nt][reg] + bias;
            lds[w][row * 136 + nt * 16 + colx] = (f16)v;
            if (node < N) {
                h[(size_t)node * 128 + nt * 16 + colx] = v;
                hh[(size_t)node * 128 + nt * 16 + colx] = (f16)v;
            }
        }
    }
    f32x4 c2[8];
#pragma unroll
    for (int nt = 0; nt < 8; nt++) c2[nt] = (f32x4){0.f, 0.f, 0.f, 0.f};
#pragma unroll
    for (int kt = 0; kt < 4; kt++) {
        f16x8 a = *(const f16x8*)&lds[w][colx * 136 + kt * 32 + quad * 8];
#pragma unroll
        for (int nt = 0; nt < 8; nt++) {
            f16x8 b = *(const f16x8*)(mw1p + ((size_t)(kt * 8 + nt) * 64 + lane) * 8);
            c2[nt] = MFMA16(a, b, c2[nt]);
        }
    }
#pragma unroll
    for (int nt = 0; nt < 8; nt++) {
        float bias = mb1[nt * 16 + colx];
#pragma unroll
        for (int reg = 0; reg < 4; reg++) {
            int node = base + quad * 4 + reg;
            if (node < N) t[(size_t)node * 128 + nt * 16 + colx] = (f16)(c2[nt][reg] + bias);
        }
    }
}

__global__ __launch_bounds__(256) void k_scanC(const int* __restrict__ degv,
                                               const int* __restrict__ bsum,
                                               int* __restrict__ rowp, int N, int E) {
    __shared__ int lds[256];
    __shared__ int wo[4];
    int b = blockIdx.x, t = threadIdx.x;
    int idx = b * 256 + t;
    int v = (idx < N) ? degv[idx] : 0;
    lds[t] = v;
    __syncthreads();
#pragma unroll
    for (int d = 1; d < 256; d <<= 1) {
        int u = (t >= d) ? lds[t - d] : 0;
        __syncthreads();
        lds[t] += u;
        __syncthreads();
    }
    int off = 0;
    for (int j = t; j < b; j += 256) off += bsum[j];
#pragma unroll
    for (int o = 32; o; o >>= 1) off += __shfl_down(off, o, 64);
    if ((t & 63) == 0) wo[t >> 6] = off;
    __syncthreads();
    int boff = wo[0] + wo[1] + wo[2] + wo[3];
    if (idx < N) rowp[idx] = boff + lds[t] - v;
    if (b == 0 && t == 0) rowp[N] = E;
}

// Scatter edges into CSR (fused {src, edge_attr} int2 records) + fill recs e0/e1.
__global__ __launch_bounds__(256) void k_scat(const int* __restrict__ ei,
                                              const float* __restrict__ eattr,
                                              const int* __restrict__ rowp,
                                              int* __restrict__ cur,
                                              int2* __restrict__ esea,
                                              int4* __restrict__ recs,
                                              const int* __restrict__ dcnt,
                                              int E, int N) {
    int gtid = blockIdx.x * 256 + threadIdx.x;
    int gsz = gridDim.x * 256;
    for (int e = gtid; e < E; e += gsz) {
        int s = ei[e], d = ei[E + e];
        int p = rowp[d] + atomicAdd(&cur[d], 1);
        esea[p] = (int2){s, __float_as_int(eattr[e])};
    }
    for (int d4 = 0; d4 < 4; d4++) {
        int cnt = dcnt[d4];
        for (int i = gtid; i < cnt; i += gsz) {
            int4* r = &recs[(size_t)d4 * N + i];
            int u = r->x;
            r->y = rowp[u];
            r->z = rowp[u + 1];
        }
    }
}

// Per-depth msg: one wave per dst node (2-node paired prefetch).
// agg[u] = mean(relu(relu(t[src]+ea*w1row) @ mw2 + mb2)) over u's edges.
// NOTE: miss-parallelism bound (~45us @ ~11MB unique random t-rows); grid
// size and per-wave ILP are invariant (R3/R7/R8 A/B). Do NOT force
// launch_bounds: R8's (256,4) spilled (253MB scratch writes, 3x slower).
__global__ __launch_bounds__(256) void k_m(
        const f16* __restrict__ t, const float* __restrict__ mw1,
        const float* __restrict__ mb2, const f16* __restrict__ mw2p,
        const int2* __restrict__ esea,
        const int4* __restrict__ recs, const int* __restrict__ dcnt,
        int dIdx, f16* __restrict__ agg, int N) {
    const int tid = threadIdx.x;
    const int lane = tid & 63;
    const int colx = lane & 15, quad = lane >> 4;
    const int gwv = blockIdx.x * 4 + (tid >> 6), nwv = gridDim.x * 4;
    const int cnt = dcnt[dIdx];

    const float* w1r = mw1 + 128 * 128;
    f16x8 w1h[4];
#pragma unroll
    for (int kt = 0; kt < 4; kt++) {
        f32x4 q0 = *(const f32x4*)(w1r + kt * 32 + quad * 8);
        f32x4 q1 = *(const f32x4*)(w1r + kt * 32 + quad * 8 + 4);
        w1h[kt][0] = (f16)q0[0]; w1h[kt][1] = (f16)q0[1];
        w1h[kt][2] = (f16)q0[2]; w1h[kt][3] = (f16)q0[3];
        w1h[kt][4] = (f16)q1[0]; w1h[kt][5] = (f16)q1[1];
        w1h[kt][6] = (f16)q1[2]; w1h[kt][7] = (f16)q1[3];
    }
    float mb2v[8];
#pragma unroll
    for (int nt = 0; nt < 8; nt++) mb2v[nt] = mb2[nt * 16 + colx];

    struct Pre { int u, e0, e1; f16 eah; f16x8 tv[4]; };
    auto load_pre = [&](int n) {
        Pre p;
        int4 r = recs[(size_t)dIdx * N + n];
        p.u = r.x; p.e0 = r.y; p.e1 = r.z;
        int lim = p.e1 - 1; if (lim < 0) lim = 0;
        int es = p.e0 + colx; if (es > lim) es = lim;
        int2 er = esea[es];
        p.eah = (f16)__int_as_float(er.y);
        const f16* trow = t + (size_t)er.x * 128;
#pragma unroll
        for (int kt = 0; kt < 4; kt++)
            p.tv[kt] = *(const f16x8*)(trow + kt * 32 + quad * 8);
        return p;
    };
    auto build_afr = [&](const f16x8* tv, f16 eah, f16x8* afr) {
#pragma unroll
        for (int kt = 0; kt < 4; kt++) {
            f16x8 v = tv[kt];
            f16x8 o;
#pragma unroll
            for (int j = 0; j < 8; j++) {
                f16 q = v[j] + eah * w1h[kt][j];
                o[j] = q > (f16)0 ? q : (f16)0;
            }
            afr[kt] = o;
        }
    };
    auto tile_acc = [&](f16x8* afr, int bs, int e1, float* aggv) {
#pragma unroll
        for (int nt = 0; nt < 8; nt++) {
            f32x4 c = (f32x4){0.f, 0.f, 0.f, 0.f};
#pragma unroll
            for (int kt = 0; kt < 4; kt++) {
                f16x8 b = *(const f16x8*)(mw2p + ((size_t)(kt * 8 + nt) * 64 + lane) * 8);
                c = MFMA16(afr[kt], b, c);
            }
#pragma unroll
            for (int reg = 0; reg < 4; reg++)
                if (bs + quad * 4 + reg < e1) aggv[nt] += fmaxf(c[reg] + mb2v[nt], 0.f);
        }
    };
    auto process = [&](const Pre& p) {
        float aggv[8] = {0.f, 0.f, 0.f, 0.f, 0.f, 0.f, 0.f, 0.f};
        f16x8 afr[4];
        build_afr(p.tv, p.eah, afr);
        tile_acc(afr, p.e0, p.e1, aggv);
        for (int bs = p.e0 + 16; bs < p.e1; bs += 16) {
            int lim = p.e1 - 1;
            int es = bs + colx; if (es > lim) es = lim;
            int2 er = esea[es];
            f16 eah = (f16)__int_as_float(er.y);
            const f16* trow = t + (size_t)er.x * 128;
            f16x8 tv[4];
#pragma unroll
            for (int kt = 0; kt < 4; kt++)
                tv[kt] = *(const f16x8*)(trow + kt * 32 + quad * 8);
            build_afr(tv, eah, afr);
            tile_acc(afr, bs, p.e1, aggv);
        }
        int deg = p.e1 - p.e0;
        float inv = 1.f / (float)(deg > 1 ? deg : 1);
#pragma unroll
        for (int nt = 0; nt < 8; nt++) {
            float s = aggv[nt];
            s += __shfl_xor(s, 16, 64);
            s += __shfl_xor(s, 32, 64);
            if (quad == 0) agg[(size_t)p.u * 128 + nt * 16 + colx] = (f16)(s * inv);
        }
    };
    int stride2 = nwv * 2;
    for (int base = gwv * 2; base < cnt; base += stride2) {
        Pre p0 = load_pre(base);
        bool has1 = (base + 1) < cnt;
        if (has1) {
            Pre p1 = load_pre(base + 1);
            process(p0);
            process(p1);
        } else {
            process(p0);
        }
    }
}

// Per-depth update, TILED: one wave = 16 nodes of this depth.
// Reads f16 hh shadow (4 lines/node) instead of f32 h (8 lines/node) —
// node's h at its update time is still its proj value, so hh (written once
// by k_mid) is exact. NO launch_bounds cap (R8: (256,3) spilled).
__global__ __launch_bounds__(256) void k_u(
        float* h, f16* t, const f16* __restrict__ hh, const f16* __restrict__ agg,
        const f16* __restrict__ uw1p, const f16* __restrict__ uw2p,
        const f16* __restrict__ mw1p,
        const float* __restrict__ ub1, const float* __restrict__ ub2,
        const float* __restrict__ mb1,
        const int4* __restrict__ recs, const int* __restrict__ dcnt,
        int dIdx, int N) {
    __shared__ __align__(16) f16 shb[4][2][16 * 136];
    const int tid = threadIdx.x;
    const int lane = tid & 63, w = tid >> 6;
    const int colx = lane & 15, quad = lane >> 4;
    const int gwv = blockIdx.x * 4 + w, nwv = gridDim.x * 4;
    const int cnt = dcnt[dIdx];
    const int ntiles = (cnt + 15) >> 4;

    for (int tb = gwv; tb < ntiles; tb += nwv) {
        int base = tb * 16;
        int aidx = base + colx;
        int ua = (aidx < cnt) ? recs[(size_t)dIdx * N + aidx].x : 0;
        int un[4];
        bool uvalid[4];
#pragma unroll
        for (int reg = 0; reg < 4; reg++) {
            int node = base + quad * 4 + reg;
            uvalid[reg] = node < cnt;
            un[reg] = uvalid[reg] ? recs[(size_t)dIdx * N + node].x : 0;
        }

        f32x4 c1[8];
#pragma unroll
        for (int nt = 0; nt < 8; nt++) c1[nt] = (f32x4){0.f, 0.f, 0.f, 0.f};
#pragma unroll
        for (int kt = 0; kt < 8; kt++) {
            f16x8 a;
            if (kt < 4)
                a = *(const f16x8*)(hh + (size_t)ua * 128 + kt * 32 + quad * 8);
            else
                a = *(const f16x8*)(agg + (size_t)ua * 128 + (kt - 4) * 32 + quad * 8);
#pragma unroll
            for (int nt = 0; nt < 8; nt++) {
                f16x8 b = *(const f16x8*)(uw1p + ((size_t)(kt * 8 + nt) * 64 + lane) * 8);
                c1[nt] = MFMA16(a, b, c1[nt]);
            }
        }
#pragma unroll
        for (int nt = 0; nt < 8; nt++) {
            float bias = ub1[nt * 16 + colx];
#pragma unroll
            for (int reg = 0; reg < 4; reg++) {
                int row = quad * 4 + reg;
                shb[w][0][row * 136 + nt * 16 + colx] = (f16)fmaxf(c1[nt][reg] + bias, 0.f);
            }
        }
        f32x4 c2[8];
#pragma unroll
        for (int nt = 0; nt < 8; nt++) c2[nt] = (f32x4){0.f, 0.f, 0.f, 0.f};
#pragma unroll
        for (int kt = 0; kt < 4; kt++) {
            f16x8 a = *(const f16x8*)&shb[w][0][colx * 136 + kt * 32 + quad * 8];
#pragma unroll
            for (int nt = 0; nt < 8; nt++) {
                f16x8 b = *(const f16x8*)(uw2p + ((size_t)(kt * 8 + nt) * 64 + lane) * 8);
                c2[nt] = MFMA16(a, b, c2[nt]);
            }
        }
#pragma unroll
        for (int nt = 0; nt < 8; nt++) {
            float bias = ub2[nt * 16 + colx];
#pragma unroll
            for (int reg = 0; reg < 4; reg++) {
                int row = quad * 4 + reg;
                float v = fmaxf(c2[nt][reg] + bias, 0.f);
                shb[w][1][row * 136 + nt * 16 + colx] = (f16)v;
                if (uvalid[reg]) h[(size_t)un[reg] * 128 + nt * 16 + colx] = v;
            }
        }
        f32x4 c3[8];
#pragma unroll
        for (int nt = 0; nt < 8; nt++) c3[nt] = (f32x4){0.f, 0.f, 0.f, 0.f};
#pragma unroll
        for (int kt = 0; kt < 4; kt++) {
            f16x8 a = *(const f16x8*)&shb[w][1][colx * 136 + kt * 32 + quad * 8];
#pragma unroll
            for (int nt = 0; nt < 8; nt++) {
                f16x8 b = *(const f16x8*)(mw1p + ((size_t)(kt * 8 + nt) * 64 + lane) * 8);
                c3[nt] = MFMA16(a, b, c3[nt]);
            }
        }
#pragma unroll
        for (int nt = 0; nt < 8; nt++) {
            float bias = mb1[nt * 16 + colx];
#pragma unroll
            for (int reg = 0; reg < 4; reg++) {
                if (uvalid[reg])
                    t[(size_t)un[reg] * 128 + nt * 16 + colx] = (f16)(c3[nt][reg] + bias);
            }
        }
    }
}

extern "C" void kernel_launch(void* const* d_in, const int* in_sizes, int n_in,
                              void* d_out, int out_size, void* d_ws, size_t ws_size,
                              hipStream_t stream) {
    const float* x    = (const float*)d_in[0];
    const int*   ei   = (const int*)d_in[1];
    const float* eatt = (const float*)d_in[2];
    const int*   dep  = (const int*)d_in[3];
    const float* pw   = (const float*)d_in[4];
    const float* pb   = (const float*)d_in[5];
    const float* mw1  = (const float*)d_in[6];
    const float* mb1  = (const float*)d_in[7];
    const float* mw2  = (const float*)d_in[8];
    const float* mb2  = (const float*)d_in[9];
    const float* uw1  = (const float*)d_in[10];
    const float* ub1  = (const float*)d_in[11];
    const float* uw2  = (const float*)d_in[12];
    const float* ub2  = (const float*)d_in[13];
    float* h = (float*)d_out;

    int N = in_sizes[3];
    int E = in_sizes[1] / 2;
    int NB = (N + 255) / 256;
    int CB = (E + 255) / 256;

    char* ws = (char*)d_ws;
    size_t o = 0;
    auto alloc = [&](size_t bytes) -> char* {
        char* p = ws + o;
        o += (bytes + 255) & ~(size_t)255;
        return p;
    };
    f16*   t    = (f16*)alloc((size_t)N * 128 * 2);
    f16*   hh   = (f16*)alloc((size_t)N * 128 * 2);
    f16*   agg  = (f16*)alloc((size_t)N * 128 * 2);
    char*  z0   = (char*)alloc(0);
    int*   degv = (int*)alloc((size_t)N * 4);
    int*   cur  = (int*)alloc((size_t)N * 4);
    int*   dcnt = (int*)alloc(64);
    size_t zbytes = (size_t)((char*)alloc(0) - z0);
    int*   rowp = (int*)alloc((size_t)(N + 1) * 4);
    int*   bsum = (int*)alloc((size_t)NB * 4);
    int2*  esea = (int2*)alloc((size_t)E * 8);
    int4*  recs = (int4*)alloc((size_t)4 * N * 16);
    f16*   pwp  = (f16*)alloc(128 * 128 * 2);
    f16*   mw1p = (f16*)alloc(128 * 128 * 2);
    f16*   mw2p = (f16*)alloc(128 * 128 * 2);
    f16*   uw1p = (f16*)alloc(256 * 128 * 2);
    f16*   uw2p = (f16*)alloc(128 * 128 * 2);

    hipMemsetAsync(z0, 0, zbytes, stream);

    k_prep<<<48 + CB + NB, 256, 0, stream>>>(pw, mw1, mw2, uw1, uw2,
                                             pwp, mw1p, mw2p, uw1p, uw2p,
                                             ei, degv, dep, dcnt, recs, CB, E, N);
    int PB = (N + 63) / 64;
    k_mid<<<NB + PB, 256, 0, stream>>>(degv, bsum, NB, x, pwp, mw1p, pb, mb1,
                                       h, hh, t, N);
    k_scanC<<<NB, 256, 0, stream>>>(degv, bsum, rowp, N, E);
    k_scat<<<CB, 256, 0, stream>>>(ei, eatt, rowp, cur, esea, recs, dcnt, E, N);

    for (int d = 0; d < 4; d++) {
        k_m<<<1024, 256, 0, stream>>>(t, mw1, mb2, mw2p, esea, recs, dcnt,
                                      d, agg, N);
        k_u<<<256, 256, 0, stream>>>(h, t, hh, agg, uw1p, uw2p, mw1p, ub1, ub2,
                                     mb1, recs, dcnt, d, N);
    }
}

// Round 10
// 367.628 us; speedup vs baseline: 2.5571x; 1.1678x over previous
//
#include <hip/hip_runtime.h>

typedef _Float16 f16;
typedef f16 f16x2 __attribute__((ext_vector_type(2)));
typedef f16 f16x8 __attribute__((ext_vector_type(8)));
typedef float f32x4 __attribute__((ext_vector_type(4)));
typedef float f32x2 __attribute__((ext_vector_type(2)));

#define MFMA16(a, b, c) __builtin_amdgcn_mfma_f32_16x16x32_f16((a), (b), (c), 0, 0, 0)

static __device__ __forceinline__ f16x8 cvt8(const float* __restrict__ p) {
    f32x4 p0 = *(const f32x4*)p;
    f32x4 p1 = *(const f32x4*)(p + 4);
    f16x8 a;
    a[0] = (f16)p0[0]; a[1] = (f16)p0[1]; a[2] = (f16)p0[2]; a[3] = (f16)p0[3];
    a[4] = (f16)p1[0]; a[5] = (f16)p1[1]; a[6] = (f16)p1[2]; a[7] = (f16)p1[3];
    return a;
}

// Fused prep: blocks [0,48) repack weights to B-fragment order; [48,48+CB)
// count in-degrees; rest classify nodes by depth into recs[].x.
__global__ __launch_bounds__(256) void k_prep(
        const float* __restrict__ pw, const float* __restrict__ mw1,
        const float* __restrict__ mw2, const float* __restrict__ uw1,
        const float* __restrict__ uw2,
        f16* __restrict__ pwp, f16* __restrict__ mw1p, f16* __restrict__ mw2p,
        f16* __restrict__ uw1p, f16* __restrict__ uw2p,
        const int* __restrict__ ei, int* __restrict__ degv,
        const int* __restrict__ dep, int* __restrict__ dcnt,
        int4* __restrict__ recs, int CB, int E, int N) {
    __shared__ int lcnt[4];
    __shared__ int lbase[4];
    int b = blockIdx.x;
    int t = threadIdx.x;
    if (b < 48) {
        const float* W; f16* out; int fb;
        if (b < 8)       { W = pw;  out = pwp;  fb = b; }
        else if (b < 16) { W = mw1; out = mw1p; fb = b - 8; }
        else if (b < 24) { W = mw2; out = mw2p; fb = b - 16; }
        else if (b < 40) { W = uw1; out = uw1p; fb = b - 24; }
        else             { W = uw2; out = uw2p; fb = b - 40; }
        int idx = fb * 256 + t;
        int lane = idx & 63;
        int nt = (idx >> 6) & 7;
        int kt = idx >> 9;
        int colx = lane & 15, quad = lane >> 4;
        f16* o = out + (size_t)idx * 8;
        const float* wb = W + (size_t)(kt * 32 + quad * 8) * 128 + nt * 16 + colx;
#pragma unroll
        for (int j = 0; j < 8; j++) o[j] = (f16)wb[(size_t)j * 128];
    } else if (b < 48 + CB) {
        int e = (b - 48) * 256 + t;
        if (e < E) atomicAdd(&degv[ei[E + e]], 1);
    } else {
        if (t < 4) lcnt[t] = 0;
        __syncthreads();
        int v = (b - 48 - CB) * 256 + t;
        int d = (v < N) ? dep[v] : 0;
        int p = -1;
        if (d >= 1 && d <= 4) p = atomicAdd(&lcnt[d - 1], 1);
        __syncthreads();
        if (t < 4) lbase[t] = (lcnt[t] > 0) ? atomicAdd(&dcnt[t], lcnt[t]) : 0;
        __syncthreads();
        if (d >= 1 && d <= 4) recs[(size_t)(d - 1) * N + lbase[d - 1] + p].x = v;
    }
}

// Blocks [0,SB): scan stage A. Rest: proj — h = x@pw+pb (f32 out + f16 shadow
// hh); t = h@mw1[0:128]+mb1.
__global__ __launch_bounds__(256) void k_mid(
        const int* __restrict__ degv, int* __restrict__ bsum, int SB,
        const float* __restrict__ x, const f16* __restrict__ pwp,
        const f16* __restrict__ mw1p, const float* __restrict__ pb,
        const float* __restrict__ mb1, float* __restrict__ h,
        f16* __restrict__ hh, f16* __restrict__ t, int N) {
    __shared__ __align__(16) f16 lds[4][16 * 136];
    __shared__ int wsum[4];
    int tid = threadIdx.x;
    if ((int)blockIdx.x < SB) {
        int idx = blockIdx.x * 256 + tid;
        int v = (idx < N) ? degv[idx] : 0;
#pragma unroll
        for (int off = 32; off; off >>= 1) v += __shfl_down(v, off, 64);
        if ((tid & 63) == 0) wsum[tid >> 6] = v;
        __syncthreads();
        if (tid == 0) bsum[blockIdx.x] = wsum[0] + wsum[1] + wsum[2] + wsum[3];
        return;
    }
    int lane = tid & 63, w = tid >> 6;
    int colx = lane & 15, quad = lane >> 4;
    int base = ((blockIdx.x - SB) * 4 + w) * 16;
    int arow = base + colx;
    int u = arow < N ? arow : N - 1;

    f32x4 c1[8];
#pragma unroll
    for (int nt = 0; nt < 8; nt++) c1[nt] = (f32x4){0.f, 0.f, 0.f, 0.f};
#pragma unroll
    for (int kt = 0; kt < 4; kt++) {
        f16x8 a = cvt8(x + (size_t)u * 128 + kt * 32 + quad * 8);
#pragma unroll
        for (int nt = 0; nt < 8; nt++) {
            f16x8 b = *(const f16x8*)(pwp + ((size_t)(kt * 8 + nt) * 64 + lane) * 8);
            c1[nt] = MFMA16(a, b, c1[nt]);
        }
    }
#pragma unroll
    for (int nt = 0; nt < 8; nt++) {
        float bias = pb[nt * 16 + colx];
#pragma unroll
        for (int reg = 0; reg < 4; reg++) {
            int row = quad * 4 + reg;
            int node = base + row;
            float v = c1[nt][reg] + bias;
            lds[w][row * 136 + nt * 16 + colx] = (f16)v;
            if (node < N) {
                h[(size_t)node * 128 + nt * 16 + colx] = v;
                hh[(size_t)node * 128 + nt * 16 + colx] = (f16)v;
            }
        }
    }
    f32x4 c2[8];
#pragma unroll
    for (int nt = 0; nt < 8; nt++) c2[nt] = (f32x4){0.f, 0.f, 0.f, 0.f};
#pragma unroll
    for (int kt = 0; kt < 4; kt++) {
        f16x8 a = *(const f16x8*)&lds[w][colx * 136 + kt * 32 + quad * 8];
#pragma unroll
        for (int nt = 0; nt < 8; nt++) {
            f16x8 b = *(const f16x8*)(mw1p + ((size_t)(kt * 8 + nt) * 64 + lane) * 8);
            c2[nt] = MFMA16(a, b, c2[nt]);
        }
    }
#pragma unroll
    for (int nt = 0; nt < 8; nt++) {
        float bias = mb1[nt * 16 + colx];
#pragma unroll
        for (int reg = 0; reg < 4; reg++) {
            int node = base + quad * 4 + reg;
            if (node < N) t[(size_t)node * 128 + nt * 16 + colx] = (f16)(c2[nt][reg] + bias);
        }
    }
}

__global__ __launch_bounds__(256) void k_scanC(const int* __restrict__ degv,
                                               const int* __restrict__ bsum,
                                               int* __restrict__ rowp, int N, int E) {
    __shared__ int lds[256];
    __shared__ int wo[4];
    int b = blockIdx.x, t = threadIdx.x;
    int idx = b * 256 + t;
    int v = (idx < N) ? degv[idx] : 0;
    lds[t] = v;
    __syncthreads();
#pragma unroll
    for (int d = 1; d < 256; d <<= 1) {
        int u = (t >= d) ? lds[t - d] : 0;
        __syncthreads();
        lds[t] += u;
        __syncthreads();
    }
    int off = 0;
    for (int j = t; j < b; j += 256) off += bsum[j];
#pragma unroll
    for (int o = 32; o; o >>= 1) off += __shfl_down(off, o, 64);
    if ((t & 63) == 0) wo[t >> 6] = off;
    __syncthreads();
    int boff = wo[0] + wo[1] + wo[2] + wo[3];
    if (idx < N) rowp[idx] = boff + lds[t] - v;
    if (b == 0 && t == 0) rowp[N] = E;
}

// Scatter edges into CSR (fused {src, edge_attr} int2 records) + fill recs e0/e1.
__global__ __launch_bounds__(256) void k_scat(const int* __restrict__ ei,
                                              const float* __restrict__ eattr,
                                              const int* __restrict__ rowp,
                                              int* __restrict__ cur,
                                              int2* __restrict__ esea,
                                              int4* __restrict__ recs,
                                              const int* __restrict__ dcnt,
                                              int E, int N) {
    int gtid = blockIdx.x * 256 + threadIdx.x;
    int gsz = gridDim.x * 256;
    for (int e = gtid; e < E; e += gsz) {
        int s = ei[e], d = ei[E + e];
        int p = rowp[d] + atomicAdd(&cur[d], 1);
        esea[p] = (int2){s, __float_as_int(eattr[e])};
    }
    for (int d4 = 0; d4 < 4; d4++) {
        int cnt = dcnt[d4];
        for (int i = gtid; i < cnt; i += gsz) {
            int4* r = &recs[(size_t)d4 * N + i];
            int u = r->x;
            r->y = rowp[u];
            r->z = rowp[u + 1];
        }
    }
}

// Per-depth msg: one wave per dst node (2-node paired prefetch).
// agg[u] = mean(relu(relu(t[src]+ea*w1row) @ mw2 + mb2)) over u's edges.
// B-matrix (mw2p, 32 KB = all of L1) is staged ONCE per block into LDS:
// previously every edge-tile re-streamed 32 KB of B through an L1 shared
// with the random t-gather -> ~400 MB/depth of L2 traffic + L1 thrash
// (the hidden 45us). LDS reads are 2-way bank-aliased (free, m136).
// Occupancy unchanged: VGPR (~144 -> 3 blk/CU) still binds, not LDS (5/CU).
__global__ __launch_bounds__(256) void k_m(
        const f16* __restrict__ t, const float* __restrict__ mw1,
        const float* __restrict__ mb2, const f16* __restrict__ mw2p,
        const int2* __restrict__ esea,
        const int4* __restrict__ recs, const int* __restrict__ dcnt,
        int dIdx, f16* __restrict__ agg, int N) {
    __shared__ __align__(16) f16 bsm[128 * 128];  // 32 KB staged mw2p
    {
        const f16x8* s8 = (const f16x8*)mw2p;
        f16x8* d8 = (f16x8*)bsm;
        for (int i = threadIdx.x; i < 2048; i += 256) d8[i] = s8[i];
    }
    __syncthreads();

    const int tid = threadIdx.x;
    const int lane = tid & 63;
    const int colx = lane & 15, quad = lane >> 4;
    const int gwv = blockIdx.x * 4 + (tid >> 6), nwv = gridDim.x * 4;
    const int cnt = dcnt[dIdx];

    const float* w1r = mw1 + 128 * 128;
    f16x8 w1h[4];
#pragma unroll
    for (int kt = 0; kt < 4; kt++) {
        f32x4 q0 = *(const f32x4*)(w1r + kt * 32 + quad * 8);
        f32x4 q1 = *(const f32x4*)(w1r + kt * 32 + quad * 8 + 4);
        w1h[kt][0] = (f16)q0[0]; w1h[kt][1] = (f16)q0[1];
        w1h[kt][2] = (f16)q0[2]; w1h[kt][3] = (f16)q0[3];
        w1h[kt][4] = (f16)q1[0]; w1h[kt][5] = (f16)q1[1];
        w1h[kt][6] = (f16)q1[2]; w1h[kt][7] = (f16)q1[3];
    }
    float mb2v[8];
#pragma unroll
    for (int nt = 0; nt < 8; nt++) mb2v[nt] = mb2[nt * 16 + colx];

    struct Pre { int u, e0, e1; f16 eah; f16x8 tv[4]; };
    auto load_pre = [&](int n) {
        Pre p;
        int4 r = recs[(size_t)dIdx * N + n];
        p.u = r.x; p.e0 = r.y; p.e1 = r.z;
        int lim = p.e1 - 1; if (lim < 0) lim = 0;
        int es = p.e0 + colx; if (es > lim) es = lim;
        int2 er = esea[es];
        p.eah = (f16)__int_as_float(er.y);
        const f16* trow = t + (size_t)er.x * 128;
#pragma unroll
        for (int kt = 0; kt < 4; kt++)
            p.tv[kt] = *(const f16x8*)(trow + kt * 32 + quad * 8);
        return p;
    };
    auto build_afr = [&](const f16x8* tv, f16 eah, f16x8* afr) {
#pragma unroll
        for (int kt = 0; kt < 4; kt++) {
            f16x8 v = tv[kt];
            f16x8 o;
#pragma unroll
            for (int j = 0; j < 8; j++) {
                f16 q = v[j] + eah * w1h[kt][j];
                o[j] = q > (f16)0 ? q : (f16)0;
            }
            afr[kt] = o;
        }
    };
    auto tile_acc = [&](f16x8* afr, int bs, int e1, float* aggv) {
#pragma unroll
        for (int nt = 0; nt < 8; nt++) {
            f32x4 c = (f32x4){0.f, 0.f, 0.f, 0.f};
#pragma unroll
            for (int kt = 0; kt < 4; kt++) {
                f16x8 b = *(const f16x8*)&bsm[((kt * 8 + nt) * 64 + lane) * 8];
                c = MFMA16(afr[kt], b, c);
            }
#pragma unroll
            for (int reg = 0; reg < 4; reg++)
                if (bs + quad * 4 + reg < e1) aggv[nt] += fmaxf(c[reg] + mb2v[nt], 0.f);
        }
    };
    auto process = [&](const Pre& p) {
        float aggv[8] = {0.f, 0.f, 0.f, 0.f, 0.f, 0.f, 0.f, 0.f};
        f16x8 afr[4];
        build_afr(p.tv, p.eah, afr);
        tile_acc(afr, p.e0, p.e1, aggv);
        for (int bs = p.e0 + 16; bs < p.e1; bs += 16) {
            int lim = p.e1 - 1;
            int es = bs + colx; if (es > lim) es = lim;
            int2 er = esea[es];
            f16 eah = (f16)__int_as_float(er.y);
            const f16* trow = t + (size_t)er.x * 128;
            f16x8 tv[4];
#pragma unroll
            for (int kt = 0; kt < 4; kt++)
                tv[kt] = *(const f16x8*)(trow + kt * 32 + quad * 8);
            build_afr(tv, eah, afr);
            tile_acc(afr, bs, p.e1, aggv);
        }
        int deg = p.e1 - p.e0;
        float inv = 1.f / (float)(deg > 1 ? deg : 1);
#pragma unroll
        for (int nt = 0; nt < 8; nt++) {
            float s = aggv[nt];
            s += __shfl_xor(s, 16, 64);
            s += __shfl_xor(s, 32, 64);
            if (quad == 0) agg[(size_t)p.u * 128 + nt * 16 + colx] = (f16)(s * inv);
        }
    };
    int stride2 = nwv * 2;
    for (int base = gwv * 2; base < cnt; base += stride2) {
        Pre p0 = load_pre(base);
        bool has1 = (base + 1) < cnt;
        if (has1) {
            Pre p1 = load_pre(base + 1);
            process(p0);
            process(p1);
        } else {
            process(p0);
        }
    }
}

// Per-depth update, TILED: one wave = 16 nodes of this depth.
// Reads f16 hh shadow (4 lines/node) instead of f32 h (8 lines/node).
// NO launch_bounds cap (R8: (256,3) spilled).
__global__ __launch_bounds__(256) void k_u(
        float* h, f16* t, const f16* __restrict__ hh, const f16* __restrict__ agg,
        const f16* __restrict__ uw1p, const f16* __restrict__ uw2p,
        const f16* __restrict__ mw1p,
        const float* __restrict__ ub1, const float* __restrict__ ub2,
        const float* __restrict__ mb1,
        const int4* __restrict__ recs, const int* __restrict__ dcnt,
        int dIdx, int N) {
    __shared__ __align__(16) f16 shb[4][2][16 * 136];
    const int tid = threadIdx.x;
    const int lane = tid & 63, w = tid >> 6;
    const int colx = lane & 15, quad = lane >> 4;
    const int gwv = blockIdx.x * 4 + w, nwv = gridDim.x * 4;
    const int cnt = dcnt[dIdx];
    const int ntiles = (cnt + 15) >> 4;

    for (int tb = gwv; tb < ntiles; tb += nwv) {
        int base = tb * 16;
        int aidx = base + colx;
        int ua = (aidx < cnt) ? recs[(size_t)dIdx * N + aidx].x : 0;
        int un[4];
        bool uvalid[4];
#pragma unroll
        for (int reg = 0; reg < 4; reg++) {
            int node = base + quad * 4 + reg;
            uvalid[reg] = node < cnt;
            un[reg] = uvalid[reg] ? recs[(size_t)dIdx * N + node].x : 0;
        }

        f32x4 c1[8];
#pragma unroll
        for (int nt = 0; nt < 8; nt++) c1[nt] = (f32x4){0.f, 0.f, 0.f, 0.f};
#pragma unroll
        for (int kt = 0; kt < 8; kt++) {
            f16x8 a;
            if (kt < 4)
                a = *(const f16x8*)(hh + (size_t)ua * 128 + kt * 32 + quad * 8);
            else
                a = *(const f16x8*)(agg + (size_t)ua * 128 + (kt - 4) * 32 + quad * 8);
#pragma unroll
            for (int nt = 0; nt < 8; nt++) {
                f16x8 b = *(const f16x8*)(uw1p + ((size_t)(kt * 8 + nt) * 64 + lane) * 8);
                c1[nt] = MFMA16(a, b, c1[nt]);
            }
        }
#pragma unroll
        for (int nt = 0; nt < 8; nt++) {
            float bias = ub1[nt * 16 + colx];
#pragma unroll
            for (int reg = 0; reg < 4; reg++) {
                int row = quad * 4 + reg;
                shb[w][0][row * 136 + nt * 16 + colx] = (f16)fmaxf(c1[nt][reg] + bias, 0.f);
            }
        }
        f32x4 c2[8];
#pragma unroll
        for (int nt = 0; nt < 8; nt++) c2[nt] = (f32x4){0.f, 0.f, 0.f, 0.f};
#pragma unroll
        for (int kt = 0; kt < 4; kt++) {
            f16x8 a = *(const f16x8*)&shb[w][0][colx * 136 + kt * 32 + quad * 8];
#pragma unroll
            for (int nt = 0; nt < 8; nt++) {
                f16x8 b = *(const f16x8*)(uw2p + ((size_t)(kt * 8 + nt) * 64 + lane) * 8);
                c2[nt] = MFMA16(a, b, c2[nt]);
            }
        }
#pragma unroll
        for (int nt = 0; nt < 8; nt++) {
            float bias = ub2[nt * 16 + colx];
#pragma unroll
            for (int reg = 0; reg < 4; reg++) {
                int row = quad * 4 + reg;
                float v = fmaxf(c2[nt][reg] + bias, 0.f);
                shb[w][1][row * 136 + nt * 16 + colx] = (f16)v;
                if (uvalid[reg]) h[(size_t)un[reg] * 128 + nt * 16 + colx] = v;
            }
        }
        f32x4 c3[8];
#pragma unroll
        for (int nt = 0; nt < 8; nt++) c3[nt] = (f32x4){0.f, 0.f, 0.f, 0.f};
#pragma unroll
        for (int kt = 0; kt < 4; kt++) {
            f16x8 a = *(const f16x8*)&shb[w][1][colx * 136 + kt * 32 + quad * 8];
#pragma unroll
            for (int nt = 0; nt < 8; nt++) {
                f16x8 b = *(const f16x8*)(mw1p + ((size_t)(kt * 8 + nt) * 64 + lane) * 8);
                c3[nt] = MFMA16(a, b, c3[nt]);
            }
        }
#pragma unroll
        for (int nt = 0; nt < 8; nt++) {
            float bias = mb1[nt * 16 + colx];
#pragma unroll
            for (int reg = 0; reg < 4; reg++) {
                if (uvalid[reg])
                    t[(size_t)un[reg] * 128 + nt * 16 + colx] = (f16)(c3[nt][reg] + bias);
            }
        }
    }
}

extern "C" void kernel_launch(void* const* d_in, const int* in_sizes, int n_in,
                              void* d_out, int out_size, void* d_ws, size_t ws_size,
                              hipStream_t stream) {
    const float* x    = (const float*)d_in[0];
    const int*   ei   = (const int*)d_in[1];
    const float* eatt = (const float*)d_in[2];
    const int*   dep  = (const int*)d_in[3];
    const float* pw   = (const float*)d_in[4];
    const float* pb   = (const float*)d_in[5];
    const float* mw1  = (const float*)d_in[6];
    const float* mb1  = (const float*)d_in[7];
    const float* mw2  = (const float*)d_in[8];
    const float* mb2  = (const float*)d_in[9];
    const float* uw1  = (const float*)d_in[10];
    const float* ub1  = (const float*)d_in[11];
    const float* uw2  = (const float*)d_in[12];
    const float* ub2  = (const float*)d_in[13];
    float* h = (float*)d_out;

    int N = in_sizes[3];
    int E = in_sizes[1] / 2;
    int NB = (N + 255) / 256;
    int CB = (E + 255) / 256;

    char* ws = (char*)d_ws;
    size_t o = 0;
    auto alloc = [&](size_t bytes) -> char* {
        char* p = ws + o;
        o += (bytes + 255) & ~(size_t)255;
        return p;
    };
    f16*   t    = (f16*)alloc((size_t)N * 128 * 2);
    f16*   hh   = (f16*)alloc((size_t)N * 128 * 2);
    f16*   agg  = (f16*)alloc((size_t)N * 128 * 2);
    char*  z0   = (char*)alloc(0);
    int*   degv = (int*)alloc((size_t)N * 4);
    int*   cur  = (int*)alloc((size_t)N * 4);
    int*   dcnt = (int*)alloc(64);
    size_t zbytes = (size_t)((char*)alloc(0) - z0);
    int*   rowp = (int*)alloc((size_t)(N + 1) * 4);
    int*   bsum = (int*)alloc((size_t)NB * 4);
    int2*  esea = (int2*)alloc((size_t)E * 8);
    int4*  recs = (int4*)alloc((size_t)4 * N * 16);
    f16*   pwp  = (f16*)alloc(128 * 128 * 2);
    f16*   mw1p = (f16*)alloc(128 * 128 * 2);
    f16*   mw2p = (f16*)alloc(128 * 128 * 2);
    f16*   uw1p = (f16*)alloc(256 * 128 * 2);
    f16*   uw2p = (f16*)alloc(128 * 128 * 2);

    hipMemsetAsync(z0, 0, zbytes, stream);

    k_prep<<<48 + CB + NB, 256, 0, stream>>>(pw, mw1, mw2, uw1, uw2,
                                             pwp, mw1p, mw2p, uw1p, uw2p,
                                             ei, degv, dep, dcnt, recs, CB, E, N);
    int PB = (N + 63) / 64;
    k_mid<<<NB + PB, 256, 0, stream>>>(degv, bsum, NB, x, pwp, mw1p, pb, mb1,
                                       h, hh, t, N);
    k_scanC<<<NB, 256, 0, stream>>>(degv, bsum, rowp, N, E);
    k_scat<<<CB, 256, 0, stream>>>(ei, eatt, rowp, cur, esea, recs, dcnt, E, N);

    for (int d = 0; d < 4; d++) {
        k_m<<<1024, 256, 0, stream>>>(t, mw1, mb2, mw2p, esea, recs, dcnt,
                                      d, agg, N);
        k_u<<<256, 256, 0, stream>>>(h, t, hh, agg, uw1p, uw2p, mw1p, ub1, ub2,
                                     mb1, recs, dcnt, d, N);
    }
}